// Round 2
// baseline (232.593 us; speedup 1.0000x reference)
//
#include <hip/hip_runtime.h>
#include <hip/hip_bf16.h>
#include <stdint.h>

typedef __attribute__((ext_vector_type(8))) short short8;
typedef __attribute__((ext_vector_type(4))) float f32x4;
typedef __attribute__((ext_vector_type(16))) float f32x16;
typedef __attribute__((ext_vector_type(4))) unsigned short ushort4v;
typedef __attribute__((ext_vector_type(4))) unsigned int uint4v;

#define TT 2048
#define HH 16
#define CCdim 1024
#define BT 4096   // B*T

// round-to-nearest-even f32 -> bf16 (matches jnp astype)
__device__ inline unsigned short f2bf(float f) {
  unsigned u = __float_as_uint(f);
  u += 0x7FFF + ((u >> 16) & 1);
  return (unsigned short)(u >> 16);
}
__device__ inline float bf2f(unsigned short s) {
  return __uint_as_float(((unsigned)s) << 16);
}
__device__ inline unsigned pack2(float a, float b) {
  return (unsigned)f2bf(a) | ((unsigned)f2bf(b) << 16);
}

__device__ inline void gload16(const unsigned short* g, unsigned short* l) {
  __builtin_amdgcn_global_load_lds((const __attribute__((address_space(1))) void*)g,
                                   (__attribute__((address_space(3))) void*)l, 16, 0, 0);
}

// ---------------- prep: casts + bf16-rounded rope table ----------------
__global__ __launch_bounds__(256) void prep(const float* __restrict__ x, const float* __restrict__ wq,
                     const float* __restrict__ wk, const float* __restrict__ wv,
                     const float* __restrict__ wp, unsigned short* __restrict__ xb,
                     unsigned short* __restrict__ wqkv, unsigned short* __restrict__ wpb,
                     float2* __restrict__ tab) {
  long idx = (long)blockIdx.x * blockDim.x + threadIdx.x;
  const long NX = (long)BT * CCdim;        // 4194304
  const long NW = (long)CCdim * CCdim;     // 1048576
  if (idx < NX) { xb[idx] = f2bf(x[idx]); return; }
  idx -= NX;
  if (idx < NW) { wqkv[idx] = f2bf(wq[idx]); return; }
  idx -= NW;
  if (idx < NW) { wqkv[NW + idx] = f2bf(wk[idx]); return; }
  idx -= NW;
  if (idx < NW) { wqkv[2 * NW + idx] = f2bf(wv[idx]); return; }
  idx -= NW;
  if (idx < NW) { wpb[idx] = f2bf(wp[idx]); return; }
  idx -= NW;
  if (idx < (long)TT * 32) {
    int t = (int)(idx >> 5), i = (int)(idx & 31);
    float invf = powf(10000.0f, -(float)i / 32.0f);
    float a = (float)t * invf;
    tab[idx] = make_float2(bf2f(f2bf(cosf(a))), bf2f(f2bf(sinf(a))));
  }
}

// ---------------- GEMM: C[m][n] = sum_k A[m][k] * W[n][k]  (both row-major, K=1024) ----
__global__ __launch_bounds__(256) void gemm_bt(const unsigned short* __restrict__ A,
                                               const unsigned short* __restrict__ W,
                                               float* __restrict__ C, int ldc) {
  __shared__ __align__(16) unsigned short As[128 * 32];
  __shared__ __align__(16) unsigned short Ws[128 * 32];
  const int K = 1024;
  const int tid = threadIdx.x;
  const int lane = tid & 63;
  const int wid = tid >> 6;
  const int wr = wid >> 1, wc = wid & 1;
  const int m0 = blockIdx.y * 128;
  const int n0 = blockIdx.x * 128;

  f32x4 acc[4][4] = {};

  const int srow0 = tid >> 2;
  const int cgrp = tid & 3;
  const int cd = (cgrp ^ ((srow0 >> 1) & 3)) * 8;
  const unsigned short* Arow0 = A + (long)(m0 + srow0) * K + cd;
  const unsigned short* Arow1 = A + (long)(m0 + srow0 + 64) * K + cd;
  const unsigned short* Wrow0 = W + (long)(n0 + srow0) * K + cd;
  const unsigned short* Wrow1 = W + (long)(n0 + srow0 + 64) * K + cd;
  unsigned short* ldsA0 = As + wid * 512;
  unsigned short* ldsA1 = As + 2048 + wid * 512;
  unsigned short* ldsW0 = Ws + wid * 512;
  unsigned short* ldsW1 = Ws + 2048 + wid * 512;

  for (int kt = 0; kt < 32; ++kt) {
    const int kof = kt * 32;
    gload16(Arow0 + kof, ldsA0);
    gload16(Arow1 + kof, ldsA1);
    gload16(Wrow0 + kof, ldsW0);
    gload16(Wrow1 + kof, ldsW1);
    asm volatile("s_waitcnt vmcnt(0)" ::: "memory");
    __syncthreads();
    short8 af[4], bf[4];
#pragma unroll
    for (int mi = 0; mi < 4; ++mi) {
      int r = wr * 64 + mi * 16 + (lane & 15);
      af[mi] = *(const short8*)&As[r * 32 + (((lane >> 4) ^ ((r >> 1) & 3)) * 8)];
    }
#pragma unroll
    for (int nj = 0; nj < 4; ++nj) {
      int r = wc * 64 + nj * 16 + (lane & 15);
      bf[nj] = *(const short8*)&Ws[r * 32 + (((lane >> 4) ^ ((r >> 1) & 3)) * 8)];
    }
#pragma unroll
    for (int mi = 0; mi < 4; ++mi)
#pragma unroll
      for (int nj = 0; nj < 4; ++nj)
        acc[mi][nj] = __builtin_amdgcn_mfma_f32_16x16x32_bf16(af[mi], bf[nj], acc[mi][nj], 0, 0, 0);
    __syncthreads();
  }
#pragma unroll
  for (int mi = 0; mi < 4; ++mi)
#pragma unroll
    for (int nj = 0; nj < 4; ++nj)
#pragma unroll
      for (int j = 0; j < 4; ++j) {
        int rr = m0 + wr * 64 + mi * 16 + 4 * (lane >> 4) + j;
        int ncol = n0 + wc * 64 + nj * 16 + (lane & 15);
        C[(long)rr * ldc + ncol] = acc[mi][nj][j];
      }
}

// ---------------- RMSNorm + RoPE on q,k; write (B,H,T,hd) bf16; fold 1/8 scale into Q ----
__global__ __launch_bounds__(256) void rmsrope(const float* __restrict__ qkv, const float* __restrict__ g,
                                               const float2* __restrict__ tab,
                                               unsigned short* __restrict__ Qh,
                                               unsigned short* __restrict__ Kh) {
  int rid = blockIdx.x * 4 + (threadIdx.x >> 6);  // (b*T + t)*H + h
  int lane = threadIdx.x & 63;
  int h = rid & 15;
  int bt = rid >> 4;
  int t = bt & (TT - 1);
  int b = bt >> 11;
  const float* src = qkv + (long)bt * 3072;
  float2 cs = tab[t * 32 + (lane & 31)];
  float gg = g[lane];
  float sgn = (lane < 32) ? 1.0f : -1.0f;
  long dst = (((long)(b * 16 + h) * TT + t)) * 64 + lane;
#pragma unroll
  for (int qk = 0; qk < 2; ++qk) {
    float u = src[qk * 1024 + h * 64 + lane];
    float ss = u * u;
    ss += __shfl_xor(ss, 1);  ss += __shfl_xor(ss, 2);  ss += __shfl_xor(ss, 4);
    ss += __shfl_xor(ss, 8);  ss += __shfl_xor(ss, 16); ss += __shfl_xor(ss, 32);
    float r = rsqrtf(ss * (1.0f / 64.0f) + 1e-5f);
    float xn = u * r * gg;
    float pr = __shfl_xor(xn, 32);
    float out = xn * cs.x + sgn * pr * cs.y;
    if (qk == 0) Qh[dst] = f2bf(out * 0.125f);
    else         Kh[dst] = f2bf(out);
  }
}

// ---------------- V repack: qkv f32 (cols 2048..3071) -> Vt bf16 (B,H,hd,T) ----------
__global__ __launch_bounds__(256) void vrepack(const float* __restrict__ qkv,
                                               unsigned short* __restrict__ Vt) {
  __shared__ __align__(16) unsigned short S[64][72];
  int blk = blockIdx.x;          // bh*32 + ttile
  int bh = blk >> 5;
  int tt = blk & 31;
  int b = bh >> 4, h = bh & 15;
  int tid = threadIdx.x;
#pragma unroll
  for (int pass = 0; pass < 4; ++pass) {
    int tl = pass * 16 + (tid >> 4);
    int cg = tid & 15;
    float4 v = *(const float4*)&qkv[(long)(b * TT + tt * 64 + tl) * 3072 + 2048 + h * 64 + cg * 4];
    ushort4v o = { f2bf(v.x), f2bf(v.y), f2bf(v.z), f2bf(v.w) };
    *(ushort4v*)&S[tl][cg * 4] = o;
  }
  __syncthreads();
  int d = tid >> 2, ts = tid & 3;
  short8 o0, o1;
#pragma unroll
  for (int t2 = 0; t2 < 8; ++t2) o0[t2] = (short)S[ts * 16 + t2][d];
#pragma unroll
  for (int t2 = 0; t2 < 8; ++t2) o1[t2] = (short)S[ts * 16 + 8 + t2][d];
  unsigned short* dst = Vt + ((long)bh * 64 + d) * TT + tt * 64 + ts * 16;
  *(short8*)dst = o0;
  *(short8*)(dst + 8) = o1;
}

// ---------------- flash attention: barrier-free, LDS-free, swapped-QK^T 32x32 MFMA ----
// One wave owns 32 q-rows; KV tile = 32. S^T = mfma(K_frag, Q_frag): lane holds 16
// scores for q-row (lane&31); partner half in lane^32. Softmax in-register; P^T
// redistributed to B-frags via 8 shfl_xor(32) + half-select; PV = mfma(V^T, P^T).
__global__ __launch_bounds__(256) void attn(const unsigned short* __restrict__ Qh,
                                            const unsigned short* __restrict__ Kh,
                                            const unsigned short* __restrict__ Vt,
                                            unsigned short* __restrict__ Y) {
  const int lane = threadIdx.x & 63;
  const int wid = threadIdx.x >> 6;
  int bid = blockIdx.x;
  bid = (bid & 7) * 64 + (bid >> 3);        // XCD swizzle (512 % 8 == 0: bijective)
  const int w = bid * 4 + wid;              // 0..2047
  const int bh = w >> 6;                    // 0..31
  const int qt = w & 63;                    // 0..63
  const int b = bh >> 4, h = bh & 15;
  const long bhT = (long)bh * TT;
  const int q0 = qt * 32;
  const int l31 = lane & 31;
  const int hk = (lane >> 5) * 8;           // k-chunk sub-offset
  const bool lob = lane < 32;

  // Q B-frags: qf[c] = Q[q0+l31][c*16 + hk .. +7]  (Q pre-scaled by 1/8)
  short8 qf[4];
  {
    const unsigned short* qp = Qh + (bhT + q0 + l31) * 64 + hk;
#pragma unroll
    for (int c = 0; c < 4; ++c) qf[c] = *(const short8*)(qp + c * 16);
  }

  const unsigned short* kp = Kh + (bhT + l31) * 64 + hk;
  const unsigned short* vp0 = Vt + ((long)bh * 64 + l31) * TT + hk;        // d-block 0
  const unsigned short* vp1 = vp0 + (long)32 * TT;                          // d-block 1

  f32x16 oacc0 = {}, oacc1 = {};
  float m = -1e30f, ell = 0.f;

  short8 kf[4];
#pragma unroll
  for (int c = 0; c < 4; ++c) kf[c] = *(const short8*)(kp + c * 16);

  for (int t = 0; t < 64; ++t) {
    // V A-frags for current tile (latency hides under QK+softmax)
    short8 vf0[2], vf1[2];
#pragma unroll
    for (int c = 0; c < 2; ++c) {
      vf0[c] = *(const short8*)(vp0 + t * 32 + c * 16);
      vf1[c] = *(const short8*)(vp1 + t * 32 + c * 16);
    }
    // K A-frags for next tile
    short8 kn[4];
    {
      int tn = (t < 63) ? (t + 1) : 63;
      const unsigned short* kpn = kp + tn * 32 * 64;
#pragma unroll
      for (int c = 0; c < 4; ++c) kn[c] = *(const short8*)(kpn + c * 16);
    }

    // S^T[k][q] = sum_d K[kv0+k][d] Q[q0+q][d]; lane: q=l31, k=(reg&3)+8*(reg>>2)+4*(lane>>5)
    f32x16 s = {};
#pragma unroll
    for (int c = 0; c < 4; ++c)
      s = __builtin_amdgcn_mfma_f32_32x32x16_bf16(kf[c], qf[c], s, 0, 0, 0);

    // online softmax, fully per-lane for one q-row
    float mx = s[0];
#pragma unroll
    for (int r = 1; r < 16; ++r) mx = fmaxf(mx, s[r]);
    mx = fmaxf(mx, __shfl_xor(mx, 32));
    if (!__all(mx <= m + 8.0f)) {           // defer-max: skip rescale for small growth
      float mn = fmaxf(m, mx);
      float corr = __expf(m - mn);
      m = mn;
      ell *= corr;
#pragma unroll
      for (int r = 0; r < 16; ++r) { oacc0[r] *= corr; oacc1[r] *= corr; }
    }
    float p[16], ps = 0.f;
#pragma unroll
    for (int r = 0; r < 16; ++r) { p[r] = __expf(s[r] - m); ps += p[r]; }
    ell += ps;                               // per-lane half-row sum; combined at end

    // pack P^T to bf16 pairs in reg order (k ascending within own half)
    unsigned a0 = pack2(p[0], p[1]),   a1 = pack2(p[2], p[3]);
    unsigned a2 = pack2(p[4], p[5]),   a3 = pack2(p[6], p[7]);
    unsigned a4 = pack2(p[8], p[9]),   a5 = pack2(p[10], p[11]);
    unsigned a6 = pack2(p[12], p[13]), a7 = pack2(p[14], p[15]);
    unsigned x0 = __shfl_xor(a0, 32), x1 = __shfl_xor(a1, 32);
    unsigned x2 = __shfl_xor(a2, 32), x3 = __shfl_xor(a3, 32);
    unsigned x4 = __shfl_xor(a4, 32), x5 = __shfl_xor(a5, 32);
    unsigned x6 = __shfl_xor(a6, 32), x7 = __shfl_xor(a7, 32);
    // B-frag chunk0 covers k 0..15, chunk1 covers k 16..31 (lane half picks k+8)
    uint4v f0 = { lob ? a0 : x2, lob ? a1 : x3, lob ? x0 : a2, lob ? x1 : a3 };
    uint4v f1 = { lob ? a4 : x6, lob ? a5 : x7, lob ? x4 : a6, lob ? x5 : a7 };
    short8 pf0 = __builtin_bit_cast(short8, f0);
    short8 pf1 = __builtin_bit_cast(short8, f1);

    // O^T[d][q] += V^T[d][k] P^T[k][q]
    oacc0 = __builtin_amdgcn_mfma_f32_32x32x16_bf16(vf0[0], pf0, oacc0, 0, 0, 0);
    oacc0 = __builtin_amdgcn_mfma_f32_32x32x16_bf16(vf0[1], pf1, oacc0, 0, 0, 0);
    oacc1 = __builtin_amdgcn_mfma_f32_32x32x16_bf16(vf1[0], pf0, oacc1, 0, 0, 0);
    oacc1 = __builtin_amdgcn_mfma_f32_32x32x16_bf16(vf1[1], pf1, oacc1, 0, 0, 0);

#pragma unroll
    for (int c = 0; c < 4; ++c) kf[c] = kn[c];
  }

  float ellf = ell + __shfl_xor(ell, 32);
  float rinv = 1.0f / ellf;
  long rowbase = ((long)b * TT + q0 + l31) * CCdim + h * 64;
  const int dhalf = 4 * (lane >> 5);
#pragma unroll
  for (int i = 0; i < 8; ++i) {
    int d = (2 * i & 3) + 8 * (i >> 1) + dhalf;
    *(unsigned*)&Y[rowbase + d]      = pack2(oacc0[2 * i] * rinv, oacc0[2 * i + 1] * rinv);
    *(unsigned*)&Y[rowbase + 32 + d] = pack2(oacc1[2 * i] * rinv, oacc1[2 * i + 1] * rinv);
  }
}

extern "C" void kernel_launch(void* const* d_in, const int* in_sizes, int n_in,
                              void* d_out, int out_size, void* d_ws, size_t ws_size,
                              hipStream_t stream) {
  const float* x  = (const float*)d_in[0];
  const float* wq = (const float*)d_in[1];
  const float* wk = (const float*)d_in[2];
  const float* wv = (const float*)d_in[3];
  const float* wp = (const float*)d_in[4];
  const float* g  = (const float*)d_in[5];

  char* w = (char*)d_ws;
  unsigned short* xb   = (unsigned short*)w; w += (long)BT * CCdim * 2;
  unsigned short* wqkv = (unsigned short*)w; w += (long)3 * CCdim * CCdim * 2;
  unsigned short* wpb  = (unsigned short*)w; w += (long)CCdim * CCdim * 2;
  float* qkv           = (float*)w;          w += (long)BT * 3 * CCdim * 4;
  unsigned short* qh   = (unsigned short*)w; w += (long)BT * CCdim * 2;
  unsigned short* kh   = (unsigned short*)w; w += (long)BT * CCdim * 2;
  unsigned short* vt   = (unsigned short*)w; w += (long)BT * CCdim * 2;
  unsigned short* yb   = (unsigned short*)w; w += (long)BT * CCdim * 2;
  float2* tab          = (float2*)w;         w += (long)TT * 32 * 8;

  long total = (long)BT * CCdim + 4L * CCdim * CCdim + (long)TT * 32;
  int pblocks = (int)((total + 255) / 256);
  prep<<<pblocks, 256, 0, stream>>>(x, wq, wk, wv, wp, xb, wqkv, wpb, tab);
  gemm_bt<<<dim3(24, 32), 256, 0, stream>>>(xb, wqkv, qkv, 3072);
  rmsrope<<<16384, 256, 0, stream>>>(qkv, g, tab, qh, kh);
  vrepack<<<1024, 256, 0, stream>>>(qkv, vt);
  attn<<<512, 256, 0, stream>>>(qh, kh, vt, yb);
  gemm_bt<<<dim3(8, 32), 256, 0, stream>>>(yb, wpb, (float*)d_out, 1024);
}